// Round 5
// baseline (98.951 us; speedup 1.0000x reference)
//
#include <hip/hip_runtime.h>

#define H_IN   181
#define W_IN   360
#define NLAT   361
#define NLON   720
#define CIN    16
#define COUT   16
#define KSZ    3
#define NNZ    8192
#define HW     (H_IN * W_IN)               // 65160
#define KHW    (KSZ * HW)                  // 195480 float4 elems per slice
#define MAXB   48                          // per (ho,parity) capacity (mean 11.3)
#define NMIX_BLK 768                       // 3 k-planes x 256 chunks
#define XW_BYTES (4 * (size_t)KHW * 16)    // 12,510,720 B fp32 quad-packed

// Round 5. Keep r4's two-phase + workspace structure (ws poison is
// unconditional -> ws is free), remove the three measured overheads:
//  - K1 mix: grid (k, chunk) so k is block-uniform; w k-slice staged in LDS
//    as [c][co] and read as 4 broadcast ds_read_b128 per c (was 256 ds_read_b32).
//  - xw is fp32 float4 (12.5 MB; 3.1 MB per XCD-pinned slice, L2-fit):
//    no bf16 pack/unpack anywhere; K2 entry load = 1 global_load_dwordx4.
//  - K2 is LDS/sync-free: bucket segments are packed int4{base,ps,val,0} in
//    global ws, read with block-uniform addresses -> scalar s_load path.

static __device__ __forceinline__ int rfl_i(int i) {
    return __builtin_amdgcn_readfirstlane(i);
}
static __device__ __forceinline__ float rfl_f(float f) {
    return __uint_as_float(__builtin_amdgcn_readfirstlane(__float_as_uint(f)));
}
__device__ __forceinline__ void fma4(float4& a, float v, const float4& f) {
    a.x += v * f.x; a.y += v * f.y; a.z += v * f.z; a.w += v * f.w;
}

// ---------------------------------------------------------------------------
// K1: blocks [0,768) channel-mix one (k, 256-elem chunk) into fp32 quad xw;
// blocks [768, 768+361) build latitude ho's parity-sorted packed segments.
// ---------------------------------------------------------------------------
__global__ __launch_bounds__(256) void mix_bucket_kernel(
    const float* __restrict__ x,      // [CIN][H_IN][W_IN]
    const float* __restrict__ w,      // [COUT][CIN][KSZ]
    const int*   __restrict__ ker_idx,
    const int*   __restrict__ row_idx,
    const int*   __restrict__ col_idx,
    const float* __restrict__ vals,
    float4* __restrict__ xw4,         // [4][KSZ][H_IN][W_IN] float4 (co-quad)
    int*   __restrict__ gcnt,         // [NLAT][2] padded counts
    int4*  __restrict__ gseg)         // [NLAT][2][MAXB] {base, ps, valbits, 0}
{
    const int tid = threadIdx.x;

    if (blockIdx.x >= NMIX_BLK) {
        // ---- parity-sorted packed bucket build for latitude ho ----
        const int ho = blockIdx.x - NMIX_BLK;
        __shared__ int   s_cnt[2];
        __shared__ int   s_b [2 * MAXB];
        __shared__ int   s_ps[2 * MAXB];
        __shared__ float s_v [2 * MAXB];

        if (tid < 2) s_cnt[tid] = 0;
        if (tid < 2 * MAXB) { s_b[tid] = 0; s_ps[tid] = 0; s_v[tid] = 0.f; }
        __syncthreads();

        const int cbase = ho * NLON;
        const int4* __restrict__ col4 = (const int4*)col_idx;
        for (int n4 = tid; n4 < NNZ / 4; n4 += 256) {
            const int4 c4 = col4[n4];
#pragma unroll
            for (int j = 0; j < 4; ++j) {
                const int c = (j == 0) ? c4.x : (j == 1) ? c4.y : (j == 2) ? c4.z : c4.w;
                const unsigned d = (unsigned)(c - cbase);   // <720 iff lat==ho
                if (d < (unsigned)NLON) {
                    const int n    = 4 * n4 + j;
                    const int pe   = (int)(d & 1u);
                    const int slot = atomicAdd(&s_cnt[pe], 1);
                    if (slot < MAXB) {
                        // base in float4 units: (k*H + row)*W
                        s_b [pe * MAXB + slot] = (ker_idx[n] * H_IN + row_idx[n]) * W_IN;
                        s_ps[pe * MAXB + slot] = (int)(d >> 1);
                        s_v [pe * MAXB + slot] = vals[n];
                    }
                }
            }
        }
        __syncthreads();
        if (tid < 2) {
            int c = s_cnt[tid] < MAXB ? s_cnt[tid] : MAXB;
            gcnt[ho * 2 + tid] = (c + 3) & ~3;   // x4-padded; pad slots are zero
        }
        for (int i = tid; i < 2 * MAXB; i += 256) {
            gseg[ho * 2 * MAXB + i] =
                make_int4(s_b[i], s_ps[i], __float_as_int(s_v[i]), 0);
        }
        return;
    }

    // ---- channel mix for one (k, chunk): k is block-uniform ----
    const int k   = blockIdx.x >> 8;          // 0..2
    const int pos = (blockIdx.x & 255) * 256 + tid;

    __shared__ float sw[CIN * COUT];          // k-slice, layout [c][co]
    {
        const int co = tid & 15, c = tid >> 4;
        sw[tid] = w[(co * CIN + c) * KSZ + k];
    }
    __syncthreads();

    if (pos >= HW) return;

    float4 a0 = make_float4(0.f, 0.f, 0.f, 0.f), a1 = a0, a2 = a0, a3 = a0;
#pragma unroll
    for (int c = 0; c < CIN; ++c) {
        const float xv = x[c * HW + pos];
        const float4* wr = (const float4*)(sw + c * COUT);   // 4 broadcast b128
        fma4(a0, xv, wr[0]);
        fma4(a1, xv, wr[1]);
        fma4(a2, xv, wr[2]);
        fma4(a3, xv, wr[3]);
    }

    const int e = k * HW + pos;               // elem index within a slice
    xw4[0 * KHW + e] = a0;
    xw4[1 * KHW + e] = a1;
    xw4[2 * KHW + e] = a2;
    xw4[3 * KHW + e] = a3;
}

// ---------------------------------------------------------------------------
// K2: gather. grid = 1448 (8*181): r=bid&7 pins quad q=r>>1 to an XCD pair
// (3.1MB fp32 slice L2-fit). No LDS, no sync: segment metadata is read with
// block-uniform addresses (scalar s_load path, rfl-forced). Thread t owns
// lon pair (2t, 2t+1); x4 entry unroll = 4 independent 16B loads in flight.
// ---------------------------------------------------------------------------
__global__ __launch_bounds__(384) void gather_kernel(
    const float4* __restrict__ xw4,   // [4][KSZ][H_IN][W_IN] float4
    const float* __restrict__ bias,   // [COUT]
    const int*   __restrict__ gcnt,
    const int4*  __restrict__ gseg,
    float* __restrict__ out)          // [COUT][NLAT][NLON]
{
    const int bid   = blockIdx.x;
    const int r     = bid & 7;
    const int inner = bid >> 3;             // [0,181)
    const int q     = r >> 1;
    const int ho    = inner * 2 + (r & 1);
    if (ho >= NLAT) return;                 // 4 dummy blocks
    const int tid = threadIdx.x;
    if (tid >= 360) return;
    const int t = tid;                      // lon pair (2t, 2t+1)

    const int2 cnt2 = ((const int2*)gcnt)[ho];
    const int cntE = rfl_i(cnt2.x);
    const int cntO = rfl_i(cnt2.y);

    const float4 bq = ((const float4*)bias)[q];
    float4 accE = bq, accO = bq;
    const float4* __restrict__ slice = xw4 + (size_t)q * KHW;
    const int4*  __restrict__ seg    = gseg + ho * 2 * MAXB;

    // x4-unrolled parity segment: counts are multiples of 4, pads have v=0
#define SEG(PE, CNT, ACC)                                                       \
    for (int e = 0; e < (CNT); e += 4) {                                        \
        const int4 s0 = seg[(PE) * MAXB + e + 0];                               \
        const int4 s1 = seg[(PE) * MAXB + e + 1];                               \
        const int4 s2 = seg[(PE) * MAXB + e + 2];                               \
        const int4 s3 = seg[(PE) * MAXB + e + 3];                               \
        const int   b0 = rfl_i(s0.x), b1 = rfl_i(s1.x);                         \
        const int   b2 = rfl_i(s2.x), b3 = rfl_i(s3.x);                         \
        const int   p0 = rfl_i(s0.y), p1 = rfl_i(s1.y);                         \
        const int   p2 = rfl_i(s2.y), p3 = rfl_i(s3.y);                         \
        const float v0 = rfl_f(__int_as_float(s0.z));                           \
        const float v1 = rfl_f(__int_as_float(s1.z));                           \
        const float v2 = rfl_f(__int_as_float(s2.z));                           \
        const float v3 = rfl_f(__int_as_float(s3.z));                           \
        int y0 = t - p0; y0 += (y0 >> 31) & 360;                                \
        int y1 = t - p1; y1 += (y1 >> 31) & 360;                                \
        int y2 = t - p2; y2 += (y2 >> 31) & 360;                                \
        int y3 = t - p3; y3 += (y3 >> 31) & 360;                                \
        const float4 f0 = slice[b0 + y0];                                       \
        const float4 f1 = slice[b1 + y1];                                       \
        const float4 f2 = slice[b2 + y2];                                       \
        const float4 f3 = slice[b3 + y3];                                       \
        fma4(ACC, v0, f0); fma4(ACC, v1, f1);                                   \
        fma4(ACC, v2, f2); fma4(ACC, v3, f3);                                   \
    }

    SEG(0, cntE, accE)
    SEG(1, cntO, accO)
#undef SEG

    const float2 rr[4] = { make_float2(accE.x, accO.x), make_float2(accE.y, accO.y),
                           make_float2(accE.z, accO.z), make_float2(accE.w, accO.w) };
#pragma unroll
    for (int j = 0; j < 4; ++j) {
        const int co = 4 * q + j;
        *(float2*)(out + ((size_t)co * NLAT + ho) * NLON + 2 * t) = rr[j];
    }
}

// ---------------------------------------------------------------------------
extern "C" void kernel_launch(void* const* d_in, const int* in_sizes, int n_in,
                              void* d_out, int out_size, void* d_ws, size_t ws_size,
                              hipStream_t stream) {
    const float* x       = (const float*)d_in[0];
    const float* weight  = (const float*)d_in[1];
    const float* bias    = (const float*)d_in[2];
    const int*   ker_idx = (const int*)d_in[3];
    const int*   row_idx = (const int*)d_in[4];
    const int*   col_idx = (const int*)d_in[5];
    const float* vals    = (const float*)d_in[6];
    float* out = (float*)d_out;

    // workspace layout (poison fill is unconditional -> ws use is free)
    float4* xw4  = (float4*)d_ws;                        // 12,510,720 B
    int*    gcnt = (int*)((char*)d_ws + XW_BYTES);       // [NLAT*2]
    int4*   gseg = (int4*)((char*)d_ws + XW_BYTES + 4096); // [NLAT*2*MAXB]

    mix_bucket_kernel<<<NMIX_BLK + NLAT, 256, 0, stream>>>(
        x, weight, ker_idx, row_idx, col_idx, vals, xw4, gcnt, gseg);
    gather_kernel<<<1448, 384, 0, stream>>>(xw4, bias, gcnt, gseg, out);
}